// Round 1
// baseline (95.816 us; speedup 1.0000x reference)
//
#include <hip/hip_runtime.h>

#define W   4096
#define NT  256
#define PT  (W / NT)   // 16 keys per thread

__global__ __launch_bounds__(NT) void extrema_nms_kernel(
    const float* __restrict__ x,
    const int*   __restrict__ dist_p,
    float*       __restrict__ out)
{
    const int sig = blockIdx.x;
    const float* xg = x + (size_t)sig * W;
    float*       og = out + (size_t)sig * W;
    const int dist = *dist_p;

    __shared__ float xs[W];                       // 16 KB
    __shared__ unsigned long long key[W];         // 32 KB
    __shared__ unsigned long long red[NT / 64];

    const int tid = threadIdx.x;

    // Zero output (harness poisons d_out; we must produce zeros everywhere
    // except kept extrema) and stage x into LDS.
    for (int i = tid; i < W; i += NT) {
        og[i] = 0.0f;
        xs[i] = xg[i];
    }
    __syncthreads();

    // Extrema mask -> packed priority key.
    // key = (abs_bits << 32) | (W-1-i); 0 means "not a live candidate".
    for (int i = tid; i < W; i += NT) {
        float xi = xs[i];
        bool right = (i < W - 1) ? ((xs[i + 1] - xi) > 0.0f) : false; // pad right with 0 -> false
        bool left  = (i > 0)     ? ((xi - xs[i - 1]) <= 0.0f) : true; // pad left with 0 -> true
        bool s     = (xi <= 0.0f);                                     // (1 - sign(x)) as bool
        bool valley = right && left && s;
        bool peak   = (!right) && (!left) && (!s);
        unsigned int ab = __float_as_uint(xi) & 0x7fffffffu;
        key[i] = (valley || peak)
                   ? ((((unsigned long long)ab) << 32) |
                      (unsigned long long)(unsigned int)(W - 1 - i))
                   : 0ULL;
    }
    __syncthreads();

    // Greedy NMS: repeatedly take the global max-priority candidate,
    // emit it, kill everything within +/- dist.
    for (;;) {
        // per-thread max over strided keys (stride NT -> 4-way LDS bank conflict only)
        unsigned long long m = 0ULL;
        #pragma unroll
        for (int j = 0; j < PT; ++j) {
            unsigned long long k = key[tid + j * NT];
            m = (k > m) ? k : m;
        }
        // wave (64-lane) reduce
        #pragma unroll
        for (int off = 32; off > 0; off >>= 1) {
            unsigned long long o = __shfl_down(m, off, 64);
            m = (o > m) ? o : m;
        }
        if ((tid & 63) == 0) red[tid >> 6] = m;
        __syncthreads();
        if (tid == 0) {
            unsigned long long w0 = red[0];
            #pragma unroll
            for (int w2 = 1; w2 < NT / 64; ++w2)
                w0 = (red[w2] > w0) ? red[w2] : w0;
            red[0] = w0;
        }
        __syncthreads();
        const unsigned long long win = red[0];
        if (win == 0ULL) break;   // no live candidates left (uniform branch)

        const int p = (W - 1) - (int)(win & 0xffffffffu);
        if (tid == 0) og[p] = xs[p];          // emit kept extremum

        int lo = p - dist; lo = lo < 0 ? 0 : lo;
        int hi = p + dist; hi = hi > (W - 1) ? (W - 1) : hi;
        for (int j = lo + tid; j <= hi; j += NT) key[j] = 0ULL;  // kill window (incl. p)
        __syncthreads();
    }
}

extern "C" void kernel_launch(void* const* d_in, const int* in_sizes, int n_in,
                              void* d_out, int out_size, void* d_ws, size_t ws_size,
                              hipStream_t stream) {
    const float* x      = (const float*)d_in[0];
    const int*   dist_p = (const int*)d_in[1];
    float*       out    = (float*)d_out;
    const int nsig = in_sizes[0] / W;   // 128 signals of length 4096
    hipLaunchKernelGGL(extrema_nms_kernel, dim3(nsig), dim3(NT), 0, stream,
                       x, dist_p, out);
}